// Round 1
// baseline (361.892 us; speedup 1.0000x reference)
//
#include <hip/hip_runtime.h>
#include <cstdint>
#include <cstddef>

typedef __attribute__((ext_vector_type(8))) short short8;
typedef __attribute__((ext_vector_type(4))) float f32x4;

#define DEV static __device__ __forceinline__

DEV float bf2f(short s) {
  union { unsigned u; float f; } c; c.u = ((unsigned)(unsigned short)s) << 16; return c.f;
}
DEV short f2bf(float f) {
  union { float f; unsigned u; } c; c.f = f;
  unsigned r = c.u + 0x7FFFu + ((c.u >> 16) & 1u);
  return (short)(r >> 16);
}

DEV void gload_lds16(const void* g, void* l) {
  __builtin_amdgcn_global_load_lds((const __attribute__((address_space(1))) void*)g,
                                   (__attribute__((address_space(3))) void*)l, 16, 0, 0);
}

// ---------------- fp32 -> bf16 convert, 8 elems/thread ----------------
__global__ __launch_bounds__(256) void cvt_bf16(const float* __restrict__ s,
                                                short* __restrict__ d, int n8) {
  int i = blockIdx.x * 256 + threadIdx.x;
  if (i >= n8) return;
  const float4* sp = (const float4*)s + (size_t)i * 2;
  float4 a = sp[0], b = sp[1];
  short8 o;
  o[0] = f2bf(a.x); o[1] = f2bf(a.y); o[2] = f2bf(a.z); o[3] = f2bf(a.w);
  o[4] = f2bf(b.x); o[5] = f2bf(b.y); o[6] = f2bf(b.z); o[7] = f2bf(b.w);
  *((short8*)d + i) = o;
}

// ---------------- GEMM: C[m][n] = sum_k A[m][k] * W[n][k] (+bias) ----------------
// MODE 0: A = Xbf [8192,1024], nt covers 3 matrices (q,k,v), scatter to [BH,S,64] bf16
// MODE 1: A = Ybf [8192,1024], W = Wo, write fp32 out + bo
template<int MODE>
__global__ __launch_bounds__(256) void gemm_bt(
    const short* __restrict__ A, const short* __restrict__ W,
    const float* __restrict__ biasA, const float* __restrict__ biasB,
    short* __restrict__ Oq, short* __restrict__ Ok, short* __restrict__ Ov,
    float* __restrict__ Of)
{
  __shared__ short As[128 * 32];
  __shared__ short Bs[128 * 32];
  const int tid = threadIdx.x, w = tid >> 6, lane = tid & 63;
  const int lr = lane & 15, lg = lane >> 4;
  const int m0 = blockIdx.x * 128;
  const int nt = blockIdx.y;
  int mat = 0, n0;
  const short* Wm;
  if (MODE == 0) { mat = nt >> 3; n0 = (nt & 7) * 128; Wm = W + (size_t)mat * 1048576; }
  else           { n0 = nt * 128; Wm = W; }
  const int wr = (w >> 1) * 64, wc = (w & 1) * 64;
  const int srow = w * 16 + (lane >> 2), scol = (lane & 3) * 8;
  const short* ga = A  + (size_t)(m0 + srow) * 1024 + scol;
  const short* gb = Wm + (size_t)(n0 + srow) * 1024 + scol;

  f32x4 acc[4][4];
  const f32x4 fz = {0.f, 0.f, 0.f, 0.f};
  #pragma unroll
  for (int i = 0; i < 4; ++i)
    #pragma unroll
    for (int j = 0; j < 4; ++j) acc[i][j] = fz;

  for (int kk = 0; kk < 1024; kk += 32) {
    // stage A,B tiles (128x32 bf16 each) via async global->LDS, 16B/lane
    gload_lds16(ga + kk,         (char*)As + w * 1024);
    gload_lds16(ga + 65536 + kk, (char*)As + 4096 + w * 1024);
    gload_lds16(gb + kk,         (char*)Bs + w * 1024);
    gload_lds16(gb + 65536 + kk, (char*)Bs + 4096 + w * 1024);
    asm volatile("s_waitcnt vmcnt(0)" ::: "memory");
    __syncthreads();
    short8 af[4], bfv[4];
    #pragma unroll
    for (int i = 0; i < 4; ++i) af[i]  = *(const short8*)&As[(wr + i * 16 + lr) * 32 + lg * 8];
    #pragma unroll
    for (int i = 0; i < 4; ++i) bfv[i] = *(const short8*)&Bs[(wc + i * 16 + lr) * 32 + lg * 8];
    #pragma unroll
    for (int mi = 0; mi < 4; ++mi)
      #pragma unroll
      for (int ni = 0; ni < 4; ++ni)
        acc[mi][ni] = __builtin_amdgcn_mfma_f32_16x16x32_bf16(af[mi], bfv[ni], acc[mi][ni], 0, 0, 0);
    __syncthreads();
  }

  #pragma unroll
  for (int mi = 0; mi < 4; ++mi)
  #pragma unroll
  for (int ni = 0; ni < 4; ++ni)
  #pragma unroll
  for (int r = 0; r < 4; ++r) {
    const int mrow = m0 + wr + mi * 16 + lg * 4 + r;   // C row = (l>>4)*4+r  [m89]
    const int ncol = n0 + wc + ni * 16 + lr;           // C col = l&15
    float v = acc[mi][ni][r];
    if (MODE == 0) {
      const int s = mrow >> 3, b = mrow & 7, h = ncol >> 6, dd = ncol & 63;
      const size_t off = (size_t)(b * 16 + h) * 65536 + (size_t)s * 64 + dd;
      if (mat == 0)      Oq[off] = f2bf((v + biasA[ncol]) * 0.125f);  // q: +bq, *HD^-0.5
      else if (mat == 1) Ok[off] = f2bf(v);                           // k: no bias
      else               Ov[off] = f2bf(v + biasB[ncol]);             // v: +bv
    } else {
      Of[(size_t)mrow * 1024 + ncol] = v + biasA[ncol];
    }
  }
}

// ---------------- attention: per (q-block of 64, head) ----------------
__global__ __launch_bounds__(256) void attn_fwd(
    const short* __restrict__ Q, const short* __restrict__ K,
    const short* __restrict__ V, const float* __restrict__ bias,
    short* __restrict__ AO)
{
  __shared__ short VT[64 * 72];       // V-tile transposed [d][k], padded
  __shared__ short PL[4][16 * 72];    // per-wave P strip [qrow][k], padded
  const int tid = threadIdx.x, w = tid >> 6, lane = tid & 63;
  const int lr = lane & 15, lg = lane >> 4;
  const int qb = blockIdx.x, bh = blockIdx.y;
  const int q0 = qb * 64 + w * 16;
  const short* Qh = Q + (size_t)bh * 65536;
  const short* Kh = K + (size_t)bh * 65536;
  const short* Vh = V + (size_t)bh * 65536;
  const float* Bh = bias + (size_t)bh * 1048576;

  const short8 qf0 = *(const short8*)(Qh + (q0 + lr) * 64 + lg * 8);
  const short8 qf1 = *(const short8*)(Qh + (q0 + lr) * 64 + 32 + lg * 8);

  const f32x4 fz = {0.f, 0.f, 0.f, 0.f};
  f32x4 accO[4] = {fz, fz, fz, fz};
  float mrow[4] = {-3e30f, -3e30f, -3e30f, -3e30f};
  float ssum[4] = {0.f, 0.f, 0.f, 0.f};

  for (int kt = 0; kt < 16; ++kt) {
    __syncthreads();  // protect VT from previous iteration's readers
    #pragma unroll
    for (int c = 0; c < 2; ++c) {
      const int e = c * 2048 + tid * 8;
      const int vk = e >> 6, vd = e & 63;
      short8 vv = *(const short8*)(Vh + (kt * 64 + vk) * 64 + vd);
      #pragma unroll
      for (int i = 0; i < 8; ++i) VT[(vd + i) * 72 + vk] = vv[i];
    }
    __syncthreads();

    // bias tile (the dominant HBM stream) — issue loads early
    float bb[4][4];
    #pragma unroll
    for (int n = 0; n < 4; ++n)
      #pragma unroll
      for (int r = 0; r < 4; ++r)
        bb[n][r] = Bh[(q0 + lg * 4 + r) * 1024 + kt * 64 + n * 16 + lr];

    // S = Q*K^T (K B-frags direct from global; K-tile is L1/L2 resident)
    f32x4 s[4];
    #pragma unroll
    for (int n = 0; n < 4; ++n) {
      const short* kp = Kh + (kt * 64 + n * 16 + lr) * 64;
      short8 kf0 = *(const short8*)(kp + lg * 8);
      short8 kf1 = *(const short8*)(kp + 32 + lg * 8);
      f32x4 z = fz;
      z    = __builtin_amdgcn_mfma_f32_16x16x32_bf16(qf0, kf0, z, 0, 0, 0);
      s[n] = __builtin_amdgcn_mfma_f32_16x16x32_bf16(qf1, kf1, z, 0, 0, 0);
    }
    #pragma unroll
    for (int n = 0; n < 4; ++n)
      #pragma unroll
      for (int r = 0; r < 4; ++r) s[n][r] += bb[n][r];

    // online softmax (rows live on 16-lane groups; reduce via shfl_xor 8..1)
    float tmax[4];
    #pragma unroll
    for (int r = 0; r < 4; ++r)
      tmax[r] = fmaxf(fmaxf(s[0][r], s[1][r]), fmaxf(s[2][r], s[3][r]));
    #pragma unroll
    for (int msk = 8; msk >= 1; msk >>= 1)
      #pragma unroll
      for (int r = 0; r < 4; ++r) tmax[r] = fmaxf(tmax[r], __shfl_xor(tmax[r], msk));
    float sc[4];
    #pragma unroll
    for (int r = 0; r < 4; ++r) {
      float mn = fmaxf(mrow[r], tmax[r]);
      sc[r] = __expf(mrow[r] - mn);
      mrow[r] = mn;
    }
    float ps[4] = {0.f, 0.f, 0.f, 0.f};
    #pragma unroll
    for (int n = 0; n < 4; ++n)
      #pragma unroll
      for (int r = 0; r < 4; ++r) { float p = __expf(s[n][r] - mrow[r]); s[n][r] = p; ps[r] += p; }
    #pragma unroll
    for (int msk = 8; msk >= 1; msk >>= 1)
      #pragma unroll
      for (int r = 0; r < 4; ++r) ps[r] += __shfl_xor(ps[r], msk);
    #pragma unroll
    for (int r = 0; r < 4; ++r) ssum[r] = ssum[r] * sc[r] + ps[r];
    #pragma unroll
    for (int n = 0; n < 4; ++n)
      #pragma unroll
      for (int r = 0; r < 4; ++r) accO[n][r] *= sc[r];

    // P -> wave-private LDS (acc layout) then re-read as A-frags.
    // Same-wave DS ops are in program order; compiler adds lgkmcnt for read data.
    #pragma unroll
    for (int n = 0; n < 4; ++n)
      #pragma unroll
      for (int r = 0; r < 4; ++r)
        PL[w][(lg * 4 + r) * 72 + n * 16 + lr] = f2bf(s[n][r]);

    short8 pa0 = *(const short8*)&PL[w][lr * 72 + lg * 8];
    short8 pa1 = *(const short8*)&PL[w][lr * 72 + 32 + lg * 8];
    #pragma unroll
    for (int n = 0; n < 4; ++n) {
      short8 vb0 = *(const short8*)&VT[(n * 16 + lr) * 72 + lg * 8];
      short8 vb1 = *(const short8*)&VT[(n * 16 + lr) * 72 + 32 + lg * 8];
      accO[n] = __builtin_amdgcn_mfma_f32_16x16x32_bf16(pa0, vb0, accO[n], 0, 0, 0);
      accO[n] = __builtin_amdgcn_mfma_f32_16x16x32_bf16(pa1, vb1, accO[n], 0, 0, 0);
    }
  }

  const int b = bh >> 4, h = bh & 15;
  #pragma unroll
  for (int n = 0; n < 4; ++n)
    #pragma unroll
    for (int r = 0; r < 4; ++r) {
      const int qrow = q0 + lg * 4 + r;
      AO[(size_t)(qrow * 8 + b) * 1024 + h * 64 + n * 16 + lr] = f2bf(accO[n][r] / ssum[r]);
    }
}

// ---------------- LayerNorm over E=1024, one row per wave ----------------
__global__ __launch_bounds__(256) void ln_fwd(
    const short* __restrict__ X, const float* __restrict__ g,
    const float* __restrict__ be, short* __restrict__ Y)
{
  const int w = threadIdx.x >> 6, lane = threadIdx.x & 63;
  const int row = blockIdx.x * 4 + w;
  const short* xp = X + (size_t)row * 1024 + lane * 16;
  short8 a = *(const short8*)xp;
  short8 b = *(const short8*)(xp + 8);
  float f[16];
  #pragma unroll
  for (int j = 0; j < 8; ++j) { f[j] = bf2f(a[j]); f[8 + j] = bf2f(b[j]); }
  float sum = 0.f, sq = 0.f;
  #pragma unroll
  for (int j = 0; j < 16; ++j) { sum += f[j]; sq += f[j] * f[j]; }
  #pragma unroll
  for (int msk = 32; msk >= 1; msk >>= 1) { sum += __shfl_xor(sum, msk); sq += __shfl_xor(sq, msk); }
  const float mu = sum * (1.f / 1024.f);
  const float var = sq * (1.f / 1024.f) - mu * mu;
  const float rs = rsqrtf(var + 1e-5f);
  const int cb = lane * 16;
  short8 o0, o1;
  #pragma unroll
  for (int j = 0; j < 8; ++j) {
    o0[j] = f2bf((f[j] - mu) * rs * g[cb + j] + be[cb + j]);
    o1[j] = f2bf((f[8 + j] - mu) * rs * g[cb + 8 + j] + be[cb + 8 + j]);
  }
  *(short8*)(Y + (size_t)row * 1024 + cb) = o0;
  *(short8*)(Y + (size_t)row * 1024 + cb + 8) = o1;
}

extern "C" void kernel_launch(void* const* d_in, const int* in_sizes, int n_in,
                              void* d_out, int out_size, void* d_ws, size_t ws_size,
                              hipStream_t stream) {
  (void)in_sizes; (void)n_in; (void)out_size; (void)ws_size;
  const float* query = (const float*)d_in[0];
  const float* bias  = (const float*)d_in[1];
  const float* Wq    = (const float*)d_in[2];
  const float* bq    = (const float*)d_in[3];
  const float* Wk    = (const float*)d_in[4];
  const float* Wv    = (const float*)d_in[5];
  const float* bv    = (const float*)d_in[6];
  const float* Wo    = (const float*)d_in[7];
  const float* bo    = (const float*)d_in[8];
  const float* lng   = (const float*)d_in[9];
  const float* lnb   = (const float*)d_in[10];
  float* out = (float*)d_out;
  char* ws = (char*)d_ws;

  // workspace layout (72 MB total, with lifetime reuse)
  short* Wbf = (short*)ws;                     // 4x[1024x1024] bf16: 8 MB (q,k,v,o)
  short* Xbf = (short*)(ws + (8u << 20));      // [8192,1024] bf16: 16 MB
  short* Qbf = (short*)(ws + (24u << 20));     // [128,1024,64] bf16: 16 MB
  short* Kbf = (short*)(ws + (40u << 20));
  short* Vbf = (short*)(ws + (56u << 20));     // ends at 72 MB
  short* AO  = Xbf;                            // reuse: X dead after QKV proj
  short* Ybf = Qbf;                            // reuse: Q dead after attention

  cvt_bf16<<<4096, 256, 0, stream>>>(query, Xbf, 1048576);
  cvt_bf16<<<512, 256, 0, stream>>>(Wq, Wbf,           131072);
  cvt_bf16<<<512, 256, 0, stream>>>(Wk, Wbf + 1048576, 131072);
  cvt_bf16<<<512, 256, 0, stream>>>(Wv, Wbf + 2097152, 131072);
  cvt_bf16<<<512, 256, 0, stream>>>(Wo, Wbf + 3145728, 131072);

  gemm_bt<0><<<dim3(64, 24), 256, 0, stream>>>(Xbf, Wbf, bq, bv, Qbf, Kbf, Vbf, nullptr);
  attn_fwd<<<dim3(16, 128), 256, 0, stream>>>(Qbf, Kbf, Vbf, bias, AO);
  ln_fwd<<<2048, 256, 0, stream>>>(AO, lng, lnb, Ybf);
  gemm_bt<1><<<dim3(64, 8), 256, 0, stream>>>(Ybf, Wbf + 3145728, bo, nullptr, nullptr, nullptr, nullptr, out);
}